// Round 7
// baseline (232.930 us; speedup 1.0000x reference)
//
#include <hip/hip_runtime.h>
#include <cstddef>
#include <cstdint>

#define IN_F 512
#define OUT_F 128
#define NREL 10
#define MAXBINS 16000
#define CCHUNK 32768

typedef __attribute__((ext_vector_type(8))) short short8;
typedef __attribute__((ext_vector_type(4))) float f32x4;

static const int kNSrc[NREL]   = {8000,16000,8000,16000,8000,4000,8000,4000,16000,4000};
static const int kNDst[NREL]   = {8000,16000,16000,8000,4000,8000,4000,8000,4000,16000};
static const int kNEdges[NREL] = {200000,800000,400000,400000,100000,100000,100000,100000,150000,150000};
static const int kRelSrcType[NREL] = {0,1,0,1,0,2,0,3,1,2};
static const int kNNodes[4] = {8000,16000,4000,4000};
static const size_t kOutOff[4] = {0, 8000ull*OUT_F, 24000ull*OUT_F, 28000ull*OUT_F};
static const size_t kHbOff[4] = {0, 8000ull*IN_F, 24000ull*IN_F, 28000ull*IN_F};
static const int kDstRels[4][4] = {{0,3,5,7},{1,2,9,-1},{4,8,-1,-1},{6,-1,-1,-1}};
static const int kNDstRels[4] = {4,3,2,1};

__device__ __forceinline__ unsigned short f2bf(float f) {
  union { float f; unsigned u; } v; v.f = f;
  unsigned r = v.u + 0x7fffu + ((v.u >> 16) & 1u);
  return (unsigned short)(r >> 16);
}
__device__ __forceinline__ void add8(float* a, uint4 u) {
  union { unsigned u; float f; } t;
  t.u = u.x << 16;        a[0] += t.f;
  t.u = u.x & 0xffff0000; a[1] += t.f;
  t.u = u.y << 16;        a[2] += t.f;
  t.u = u.y & 0xffff0000; a[3] += t.f;
  t.u = u.z << 16;        a[4] += t.f;
  t.u = u.z & 0xffff0000; a[5] += t.f;
  t.u = u.w << 16;        a[6] += t.f;
  t.u = u.w & 0xffff0000; a[7] += t.f;
}

// ---------------- h (f32) -> hb (bf16), streaming ----------------
struct CvtParams { const float* src[4]; unsigned short* dst[4]; int n8[4]; };

__global__ __launch_bounds__(256) void k_cvt(CvtParams p) {
  const int ty = blockIdx.y;
  const int i = blockIdx.x * 256 + threadIdx.x;
  if (i >= p.n8[ty]) return;
  const float4 v0 = *(const float4*)(p.src[ty] + (size_t)i * 8);
  const float4 v1 = *(const float4*)(p.src[ty] + (size_t)i * 8 + 4);
  uint4 o;
  o.x = (unsigned)f2bf(v0.x) | ((unsigned)f2bf(v0.y) << 16);
  o.y = (unsigned)f2bf(v0.z) | ((unsigned)f2bf(v0.w) << 16);
  o.z = (unsigned)f2bf(v1.x) | ((unsigned)f2bf(v1.y) << 16);
  o.w = (unsigned)f2bf(v1.z) | ((unsigned)f2bf(v1.w) << 16);
  *(uint4*)(p.dst[ty] + (size_t)i * 8) = o;
}

// ---------------- per-chunk LDS histogram -> coalesced u16 H rows ---------------------
struct CountJob { const int* idx; unsigned short* H; int n_edges; int nbins; };
struct CountParams { CountJob j[2 * NREL]; };

__global__ __launch_bounds__(1024) void k_count(CountParams p) {
  CountJob J = p.j[blockIdx.y];
  const int e0 = blockIdx.x * CCHUNK;
  if (e0 >= J.n_edges) return;
  __shared__ int lb[MAXBINS];
  const int t = threadIdx.x;
  for (int d = t; d < J.nbins; d += 1024) lb[d] = 0;
  __syncthreads();
  const int eend = (e0 + CCHUNK < J.n_edges) ? e0 + CCHUNK : J.n_edges;
  for (int e = e0 + t; e < eend; e += 1024) atomicAdd(&lb[J.idx[e]], 1);
  __syncthreads();
  unsigned short* Hrow = J.H + (size_t)blockIdx.x * J.nbins;
  for (int d = t; d < J.nbins; d += 1024) Hrow[d] = (unsigned short)lb[d];
}

// ---------------- column-sum of H -> totals, coalesced --------------------------------
struct SumJob { const unsigned short* H; int* tot; int nbins; int nblocks; };
struct SumParams { SumJob j[2 * NREL]; };

__global__ __launch_bounds__(256) void k_sum(SumParams p) {
  SumJob J = p.j[blockIdx.y];
  const int bin = blockIdx.x * 256 + threadIdx.x;
  if (bin >= J.nbins) return;
  int s = 0;
  for (int b = 0; b < J.nblocks; ++b) s += J.H[(size_t)b * J.nbins + bin];
  J.tot[bin] = s;
}

// ---------------- exclusive scan (one 512-thread block per relation, n<=16384) -------
struct ScanRel { const int* tot; int* rowstart; int n; };
struct ScanParams { ScanRel r[NREL]; };

__global__ __launch_bounds__(512) void k_scan(ScanParams p) {
  ScanRel R = p.r[blockIdx.x];
  const int t = threadIdx.x;
  const int lane = t & 63, wv = t >> 6;
  const int base = t * 32;
  int v[32];
  int s = 0;
#pragma unroll
  for (int i = 0; i < 32; ++i) {
    int e = base + i;
    int x = (e < R.n) ? R.tot[e] : 0;
    v[i] = s; s += x;
  }
  int inc = s;
#pragma unroll
  for (int off = 1; off < 64; off <<= 1) {
    int u = __shfl_up(inc, off);
    if (lane >= off) inc += u;
  }
  __shared__ int wsum[8];
  if (lane == 63) wsum[wv] = inc;
  __syncthreads();
  int carry = 0, total = 0;
#pragma unroll
  for (int w = 0; w < 8; ++w) {
    int x = wsum[w];
    if (w < wv) carry += x;
    total += x;
  }
  const int tb = carry + (inc - s);
#pragma unroll
  for (int i = 0; i < 32; ++i) {
    int e = base + i;
    if (e < R.n) R.rowstart[e] = tb + v[i];
  }
  if (t == 0) R.rowstart[R.n] = total;
}

// ---------------- per-bin exclusive prefix over chunk-blocks (in place, u16) ---------
struct BasesJob { unsigned short* H; int nbins; int nblocks; };
struct BasesParams { BasesJob j[NREL]; };

__global__ __launch_bounds__(256) void k_bases(BasesParams p) {
  BasesJob J = p.j[blockIdx.y];
  const int bin = blockIdx.x * 256 + threadIdx.x;
  if (bin >= J.nbins) return;
  int run = 0;
  for (int b = 0; b < J.nblocks; ++b) {
    const size_t o = (size_t)b * J.nbins + bin;
    const int c = J.H[o];
    J.H[o] = (unsigned short)run;
    run += c;
  }
}

// ---------------- place edges via LDS cursors (no global atomics, u16 csr) -----------
struct PlaceJob { const int* src; const int* dst; const unsigned short* Hpre; const int* rowstart;
                  unsigned short* csr; int n_edges; int nbins; };
struct PlaceParams { PlaceJob j[NREL]; };

__global__ __launch_bounds__(1024) void k_place(PlaceParams p) {
  PlaceJob J = p.j[blockIdx.y];
  const int e0 = blockIdx.x * CCHUNK;
  if (e0 >= J.n_edges) return;
  __shared__ int lb[MAXBINS];
  const int t = threadIdx.x;
  const unsigned short* Hrow = J.Hpre + (size_t)blockIdx.x * J.nbins;
  for (int d = t; d < J.nbins; d += 1024) lb[d] = J.rowstart[d] + (int)Hrow[d];
  __syncthreads();
  const int eend = (e0 + CCHUNK < J.n_edges) ? e0 + CCHUNK : J.n_edges;
  for (int e = e0 + t; e < eend; e += 1024) {
    const int d = J.dst[e];
    const int pos = atomicAdd(&lb[d], 1);
    J.csr[pos] = (unsigned short)J.src[e];
  }
}

// ---------------- W -> W^T bf16 ----------------
struct WtParams { const float* W[NREL]; unsigned short* WT[NREL]; };

__global__ __launch_bounds__(256) void k_wt(WtParams p) {
  const int r = blockIdx.y;
  const int g = blockIdx.x * 256 + threadIdx.x;  // 0..16383
  const int k = g >> 5;
  const int n0 = (g & 31) * 4;
  const float4 w = *(const float4*)(p.W[r] + (size_t)k * OUT_F + n0);
  unsigned short* WT = p.WT[r];
  WT[(size_t)(n0 + 0) * IN_F + k] = f2bf(w.x);
  WT[(size_t)(n0 + 1) * IN_F + k] = f2bf(w.y);
  WT[(size_t)(n0 + 2) * IN_F + k] = f2bf(w.z);
  WT[(size_t)(n0 + 3) * IN_F + k] = f2bf(w.w);
}

// ---------------- y_r = (hb @ W_r) * deg_out^-1/2 — LDS-free direct-fragment MFMA ----
// Fragments for A and B stream global->VGPR (full-cacheline coalesced; B and hot A rows
// are L2-resident). No barriers, no LDS, 2-deep register pipeline.
struct GemmRel { const unsigned short* hb; const unsigned short* WT; unsigned short* y;
                 const int* deg_out; int n_src; };
struct GemmParams { GemmRel r[NREL]; };

#define GEMM_JOBS 723

__global__ __launch_bounds__(256) void k_gemm(GemmParams p) {
  // bijective XCD swizzle: orig -> jobid (m204)
  const int orig = blockIdx.x;
  const int xcd = orig & 7;
  const int i8 = orig >> 3;
  const int q = GEMM_JOBS / 8, rm = GEMM_JOBS % 8;   // 90, 3
  const int g = (xcd < rm ? xcd * (q + 1) : rm * (q + 1) + (xcd - rm) * q) + i8;
  // decode jobid -> (rel, rowtile); same-tile jobs adjacent for L2 A-reuse
  static const int dr[4] = {0, 2, 4, 6};
  static const int pr[3] = {1, 3, 8};
  static const int xr[2] = {5, 9};
  int rel, tile;
  if (g < 252)      { rel = dr[g & 3]; tile = g >> 2; }
  else if (g < 627) { int u = g - 252; rel = pr[u % 3]; tile = u / 3; }
  else if (g < 691) { int u = g - 627; rel = xr[u & 1]; tile = u >> 1; }
  else              { rel = 7; tile = g - 691; }

  const GemmRel R = p.r[rel];
  const int m0 = tile * 128;
  const int t = threadIdx.x;
  const int lane = t & 63, wid = t >> 6;
  const int wm = (wid >> 1) * 64, wn = (wid & 1) * 64;
  const int l16 = lane & 15;
  const int ko = (lane >> 4) * 8;   // k element offset within a 32-wide K step

  const unsigned short* pa[4];
  const unsigned short* pb[4];
#pragma unroll
  for (int f = 0; f < 4; ++f) {
    int ar = m0 + wm + f * 16 + l16;
    if (ar > R.n_src - 1) ar = R.n_src - 1;  // clamp: finite garbage, rows not written
    pa[f] = R.hb + (size_t)ar * IN_F + ko;
    pb[f] = R.WT + (size_t)(wn + f * 16 + l16) * IN_F + ko;
  }

  f32x4 acc[4][4];
#pragma unroll
  for (int i = 0; i < 4; ++i)
#pragma unroll
    for (int j = 0; j < 4; ++j) acc[i][j] = (f32x4){0.f, 0.f, 0.f, 0.f};

  short8 a0[4], b0[4], a1[4], b1[4];
#pragma unroll
  for (int f = 0; f < 4; ++f) { a0[f] = *(const short8*)(pa[f]); b0[f] = *(const short8*)(pb[f]); }

#pragma unroll 1
  for (int s = 0; s < 14; s += 2) {
#pragma unroll
    for (int f = 0; f < 4; ++f) {           // prefetch step s+1 (offset 32 elem = 64 B)
      a1[f] = *(const short8*)(pa[f] + 32);
      b1[f] = *(const short8*)(pb[f] + 32);
    }
#pragma unroll
    for (int i = 0; i < 4; ++i)
#pragma unroll
      for (int j = 0; j < 4; ++j)
        acc[i][j] = __builtin_amdgcn_mfma_f32_16x16x32_bf16(a0[i], b0[j], acc[i][j], 0, 0, 0);
#pragma unroll
    for (int f = 0; f < 4; ++f) {           // prefetch step s+2
      a0[f] = *(const short8*)(pa[f] + 64);
      b0[f] = *(const short8*)(pb[f] + 64);
    }
#pragma unroll
    for (int i = 0; i < 4; ++i)
#pragma unroll
      for (int j = 0; j < 4; ++j)
        acc[i][j] = __builtin_amdgcn_mfma_f32_16x16x32_bf16(a1[i], b1[j], acc[i][j], 0, 0, 0);
#pragma unroll
    for (int f = 0; f < 4; ++f) { pa[f] += 64; pb[f] += 64; }
  }
  // tail: s = 14, 15
#pragma unroll
  for (int f = 0; f < 4; ++f) {
    a1[f] = *(const short8*)(pa[f] + 32);
    b1[f] = *(const short8*)(pb[f] + 32);
  }
#pragma unroll
  for (int i = 0; i < 4; ++i)
#pragma unroll
    for (int j = 0; j < 4; ++j)
      acc[i][j] = __builtin_amdgcn_mfma_f32_16x16x32_bf16(a0[i], b0[j], acc[i][j], 0, 0, 0);
#pragma unroll
  for (int i = 0; i < 4; ++i)
#pragma unroll
    for (int j = 0; j < 4; ++j)
      acc[i][j] = __builtin_amdgcn_mfma_f32_16x16x32_bf16(a1[i], b1[j], acc[i][j], 0, 0, 0);

  const int r4 = (lane >> 4) * 4;  // C/D: col=lane&15, row=(lane>>4)*4+q
#pragma unroll
  for (int i = 0; i < 4; ++i) {
#pragma unroll
    for (int qq = 0; qq < 4; ++qq) {
      const int row = m0 + wm + i * 16 + r4 + qq;
      if (row < R.n_src) {
        const int d = R.deg_out[row];
        const float sc = rsqrtf((float)(d > 1 ? d : 1));
#pragma unroll
        for (int j = 0; j < 4; ++j) {
          const int col = wn + j * 16 + l16;
          R.y[(size_t)row * OUT_F + col] = f2bf(acc[i][j][qq] * sc);
        }
      }
    }
  }
}

// ---------------- gather-aggregate + bias + relu (one wave per node, 16 lanes/row) ---
struct AggRel { const int* rowstart; const unsigned short* csr; const unsigned short* y; const float* b; };
struct AggType { AggRel r[4]; int n_rels; int n_nodes; float* out; };
struct AggParams { AggType t[4]; };

__global__ __launch_bounds__(256) void k_aggregate(AggParams p) {
  const AggType& T = p.t[blockIdx.y];
  const int node = blockIdx.x * 4 + (threadIdx.x >> 6);
  if (node >= T.n_nodes) return;
  const int lane = threadIdx.x & 63;
  const int quarter = lane >> 4;        // 0..3: interleaved edge streams
  const int c8 = (lane & 15) * 8;       // 8 columns per lane
  float ac[8] = {0,0,0,0,0,0,0,0};
  float bs[8] = {0,0,0,0,0,0,0,0};
#pragma unroll
  for (int rr = 0; rr < 4; ++rr) {
    if (rr < T.n_rels) {
      const AggRel R = T.r[rr];
      const int lo = R.rowstart[node];
      const int hi = R.rowstart[node + 1];
      float rx[8] = {0,0,0,0,0,0,0,0};
      int k = lo + quarter;
      for (; k + 12 < hi; k += 16) {   // 16 edges in flight per wave
        const int s0 = R.csr[k];
        const int s1 = R.csr[k + 4];
        const int s2 = R.csr[k + 8];
        const int s3 = R.csr[k + 12];
        const uint4 u0 = *(const uint4*)(R.y + (size_t)s0 * OUT_F + c8);
        const uint4 u1 = *(const uint4*)(R.y + (size_t)s1 * OUT_F + c8);
        const uint4 u2 = *(const uint4*)(R.y + (size_t)s2 * OUT_F + c8);
        const uint4 u3 = *(const uint4*)(R.y + (size_t)s3 * OUT_F + c8);
        add8(rx, u0); add8(rx, u1); add8(rx, u2); add8(rx, u3);
      }
      for (; k < hi; k += 4) {
        const int s0 = R.csr[k];
        const uint4 u0 = *(const uint4*)(R.y + (size_t)s0 * OUT_F + c8);
        add8(rx, u0);
      }
      const int deg = hi - lo;
      const float sc = rsqrtf((float)(deg > 1 ? deg : 1));
#pragma unroll
      for (int i = 0; i < 8; ++i) ac[i] = fmaf(rx[i], sc, ac[i]);
      const float4 b0 = *(const float4*)(R.b + c8);
      const float4 b1 = *(const float4*)(R.b + c8 + 4);
      bs[0] += b0.x; bs[1] += b0.y; bs[2] += b0.z; bs[3] += b0.w;
      bs[4] += b1.x; bs[5] += b1.y; bs[6] += b1.z; bs[7] += b1.w;
    }
  }
#pragma unroll
  for (int i = 0; i < 8; ++i) {
    ac[i] += __shfl_xor(ac[i], 16);
    ac[i] += __shfl_xor(ac[i], 32);
    ac[i] += bs[i];
    ac[i] = ac[i] > 0.f ? ac[i] : 0.f;
  }
  if (quarter == 0) {
    float* dst = T.out + (size_t)node * OUT_F + c8;
    float4 o0 = {ac[0], ac[1], ac[2], ac[3]};
    float4 o1 = {ac[4], ac[5], ac[6], ac[7]};
    *(float4*)dst = o0;
    *(float4*)(dst + 4) = o1;
  }
}

// ---------------- host ----------------
extern "C" void kernel_launch(void* const* d_in, const int* in_sizes, int n_in,
                              void* d_out, int out_size, void* d_ws, size_t ws_size,
                              hipStream_t stream) {
  const float* h[4];
  for (int i = 0; i < 4; ++i) h[i] = (const float*)d_in[i];
  const float* W[NREL]; const float* b[NREL];
  const int* src[NREL]; const int* dst[NREL];
  for (int r = 0; r < NREL; ++r) {
    W[r]   = (const float*)d_in[4 + 2 * r];
    b[r]   = (const float*)d_in[5 + 2 * r];
    src[r] = (const int*)d_in[24 + 2 * r];
    dst[r] = (const int*)d_in[25 + 2 * r];
  }
  float* out = (float*)d_out;

  int nblk[NREL];
  for (int r = 0; r < NREL; ++r) nblk[r] = (kNEdges[r] + CCHUNK - 1) / CCHUNK;

  char* ws = (char*)d_ws;
  size_t off = 0;
  auto alloc = [&](size_t bytes) -> char* {
    char* p = ws + off;
    off = (off + bytes + 255) & ~(size_t)255;
    return p;
  };
  int* degO[NREL];
  { char* base = alloc((size_t)92000 * 4); size_t o = 0;
    for (int r = 0; r < NREL; ++r) { degO[r] = (int*)(base + o); o += (size_t)kNSrc[r] * 4; } }
  int* totI[NREL];
  { char* base = alloc((size_t)92000 * 4); size_t o = 0;
    for (int r = 0; r < NREL; ++r) { totI[r] = (int*)(base + o); o += (size_t)kNDst[r] * 4; } }
  int* rowst[NREL];
  { char* base = alloc((size_t)(92000 + NREL) * 4); size_t o = 0;
    for (int r = 0; r < NREL; ++r) { rowst[r] = (int*)(base + o); o += (size_t)(kNDst[r] + 1) * 4; } }
  unsigned short* csr[NREL];
  { char* base = alloc((size_t)2500000 * 2); size_t o = 0;
    for (int r = 0; r < NREL; ++r) { csr[r] = (unsigned short*)(base + o); o += (size_t)kNEdges[r] * 2; } }
  unsigned short* Hsrc[NREL]; unsigned short* Hdst[NREL];
  { size_t tot = 0;
    for (int r = 0; r < NREL; ++r) tot += (size_t)nblk[r] * (kNSrc[r] + kNDst[r]);
    char* base = alloc(tot * 2); size_t o = 0;
    for (int r = 0; r < NREL; ++r) { Hsrc[r] = (unsigned short*)(base + o); o += (size_t)nblk[r] * kNSrc[r] * 2; }
    for (int r = 0; r < NREL; ++r) { Hdst[r] = (unsigned short*)(base + o); o += (size_t)nblk[r] * kNDst[r] * 2; } }
  unsigned short* y[NREL];
  { char* base = alloc((size_t)92000 * OUT_F * 2); size_t o = 0;
    for (int r = 0; r < NREL; ++r) { y[r] = (unsigned short*)(base + o); o += (size_t)kNSrc[r] * OUT_F * 2; } }
  unsigned short* WT[NREL];
  { char* base = alloc((size_t)NREL * IN_F * OUT_F * 2); size_t o = 0;
    for (int r = 0; r < NREL; ++r) { WT[r] = (unsigned short*)(base + o); o += (size_t)IN_F * OUT_F * 2; } }
  unsigned short* hb = (unsigned short*)alloc((size_t)32000 * IN_F * 2);  // bf16 h, all types

  // h -> bf16
  CvtParams cvp;
  for (int ty = 0; ty < 4; ++ty) {
    cvp.src[ty] = h[ty];
    cvp.dst[ty] = hb + kHbOff[ty];
    cvp.n8[ty] = kNNodes[ty] * IN_F / 8;
  }
  k_cvt<<<dim3((16000 * IN_F / 8 + 255) / 256, 4), 256, 0, stream>>>(cvp);

  WtParams wp;
  for (int r = 0; r < NREL; ++r) { wp.W[r] = W[r]; wp.WT[r] = WT[r]; }
  k_wt<<<dim3(64, NREL), 256, 0, stream>>>(wp);

  int maxblk = 0;
  for (int r = 0; r < NREL; ++r) if (nblk[r] > maxblk) maxblk = nblk[r];

  CountParams cp;
  for (int r = 0; r < NREL; ++r) {
    cp.j[r]        = CountJob{src[r], Hsrc[r], kNEdges[r], kNSrc[r]};
    cp.j[NREL + r] = CountJob{dst[r], Hdst[r], kNEdges[r], kNDst[r]};
  }
  k_count<<<dim3(maxblk, 2 * NREL), 1024, 0, stream>>>(cp);

  SumParams sp2;
  for (int r = 0; r < NREL; ++r) {
    sp2.j[r]        = SumJob{Hsrc[r], degO[r], kNSrc[r], nblk[r]};
    sp2.j[NREL + r] = SumJob{Hdst[r], totI[r], kNDst[r], nblk[r]};
  }
  k_sum<<<dim3((16000 + 255) / 256, 2 * NREL), 256, 0, stream>>>(sp2);

  ScanParams sp;
  for (int r = 0; r < NREL; ++r) sp.r[r] = ScanRel{totI[r], rowst[r], kNDst[r]};
  k_scan<<<NREL, 512, 0, stream>>>(sp);

  BasesParams bp;
  for (int r = 0; r < NREL; ++r) bp.j[r] = BasesJob{Hdst[r], kNDst[r], nblk[r]};
  k_bases<<<dim3((16000 + 255) / 256, NREL), 256, 0, stream>>>(bp);

  PlaceParams pp;
  for (int r = 0; r < NREL; ++r)
    pp.j[r] = PlaceJob{src[r], dst[r], Hdst[r], rowst[r], csr[r], kNEdges[r], kNDst[r]};
  k_place<<<dim3(maxblk, NREL), 1024, 0, stream>>>(pp);

  GemmParams gp;
  for (int r = 0; r < NREL; ++r)
    gp.r[r] = GemmRel{hb + kHbOff[kRelSrcType[r]], WT[r], y[r], degO[r], kNSrc[r]};
  k_gemm<<<GEMM_JOBS, 256, 0, stream>>>(gp);

  AggParams ap;
  for (int ti = 0; ti < 4; ++ti) {
    AggType& T = ap.t[ti];
    T.n_nodes = kNNodes[ti];
    T.n_rels = kNDstRels[ti];
    T.out = out + kOutOff[ti];
    for (int j = 0; j < 4; ++j) {
      int r = kDstRels[ti][j];
      if (r < 0) r = kDstRels[ti][0];
      T.r[j] = AggRel{rowst[r], csr[r], y[r], b[r]};
    }
  }
  k_aggregate<<<dim3((16000 + 3) / 4, 4), 256, 0, stream>>>(ap);
}

// Round 8
// 199.337 us; speedup vs baseline: 1.1685x; 1.1685x over previous
//
#include <hip/hip_runtime.h>
#include <cstddef>
#include <cstdint>

#define IN_F 512
#define OUT_F 128
#define NREL 10
#define MAXBINS 16000
#define CCHUNK 32768

typedef __attribute__((ext_vector_type(8))) short short8;
typedef __attribute__((ext_vector_type(4))) float f32x4;

static const int kNSrc[NREL]   = {8000,16000,8000,16000,8000,4000,8000,4000,16000,4000};
static const int kNDst[NREL]   = {8000,16000,16000,8000,4000,8000,4000,8000,4000,16000};
static const int kNEdges[NREL] = {200000,800000,400000,400000,100000,100000,100000,100000,150000,150000};
static const int kRelSrcType[NREL] = {0,1,0,1,0,2,0,3,1,2};
static const int kNNodes[4] = {8000,16000,4000,4000};
static const size_t kOutOff[4] = {0, 8000ull*OUT_F, 24000ull*OUT_F, 28000ull*OUT_F};
static const size_t kHbOff[4] = {0, 8000ull*IN_F, 24000ull*IN_F, 28000ull*IN_F};
static const int kDstRels[4][4] = {{0,3,5,7},{1,2,9,-1},{4,8,-1,-1},{6,-1,-1,-1}};
static const int kNDstRels[4] = {4,3,2,1};

__device__ __forceinline__ unsigned short f2bf(float f) {
  union { float f; unsigned u; } v; v.f = f;
  unsigned r = v.u + 0x7fffu + ((v.u >> 16) & 1u);
  return (unsigned short)(r >> 16);
}
__device__ __forceinline__ void add8(float* a, uint4 u) {
  union { unsigned u; float f; } t;
  t.u = u.x << 16;        a[0] += t.f;
  t.u = u.x & 0xffff0000; a[1] += t.f;
  t.u = u.y << 16;        a[2] += t.f;
  t.u = u.y & 0xffff0000; a[3] += t.f;
  t.u = u.z << 16;        a[4] += t.f;
  t.u = u.z & 0xffff0000; a[5] += t.f;
  t.u = u.w << 16;        a[6] += t.f;
  t.u = u.w & 0xffff0000; a[7] += t.f;
}
// async global->LDS, 16B/lane; LDS dest = uniform base + lane*16 (m97 pattern)
__device__ __forceinline__ void gl_lds16(const unsigned short* g, unsigned short* l) {
  __builtin_amdgcn_global_load_lds(
      (const __attribute__((address_space(1))) unsigned int*)(g),
      (__attribute__((address_space(3))) unsigned int*)(l), 16, 0, 0);
}

// ---------------- h (f32) -> hb (bf16), streaming ----------------
struct CvtParams { const float* src[4]; unsigned short* dst[4]; int n8[4]; };

__global__ __launch_bounds__(256) void k_cvt(CvtParams p) {
  const int ty = blockIdx.y;
  const int i = blockIdx.x * 256 + threadIdx.x;
  if (i >= p.n8[ty]) return;
  const float4 v0 = *(const float4*)(p.src[ty] + (size_t)i * 8);
  const float4 v1 = *(const float4*)(p.src[ty] + (size_t)i * 8 + 4);
  uint4 o;
  o.x = (unsigned)f2bf(v0.x) | ((unsigned)f2bf(v0.y) << 16);
  o.y = (unsigned)f2bf(v0.z) | ((unsigned)f2bf(v0.w) << 16);
  o.z = (unsigned)f2bf(v1.x) | ((unsigned)f2bf(v1.y) << 16);
  o.w = (unsigned)f2bf(v1.z) | ((unsigned)f2bf(v1.w) << 16);
  *(uint4*)(p.dst[ty] + (size_t)i * 8) = o;
}

// ---------------- per-chunk LDS histogram -> coalesced u16 H rows ---------------------
struct CountJob { const int* idx; unsigned short* H; int n_edges; int nbins; };
struct CountParams { CountJob j[2 * NREL]; };

__global__ __launch_bounds__(1024) void k_count(CountParams p) {
  CountJob J = p.j[blockIdx.y];
  const int e0 = blockIdx.x * CCHUNK;
  if (e0 >= J.n_edges) return;
  __shared__ int lb[MAXBINS];
  const int t = threadIdx.x;
  for (int d = t; d < J.nbins; d += 1024) lb[d] = 0;
  __syncthreads();
  const int eend = (e0 + CCHUNK < J.n_edges) ? e0 + CCHUNK : J.n_edges;
  for (int e = e0 + t; e < eend; e += 1024) atomicAdd(&lb[J.idx[e]], 1);
  __syncthreads();
  unsigned short* Hrow = J.H + (size_t)blockIdx.x * J.nbins;
  for (int d = t; d < J.nbins; d += 1024) Hrow[d] = (unsigned short)lb[d];
}

// ---------------- column-sum of H -> totals, coalesced --------------------------------
struct SumJob { const unsigned short* H; int* tot; int nbins; int nblocks; };
struct SumParams { SumJob j[2 * NREL]; };

__global__ __launch_bounds__(256) void k_sum(SumParams p) {
  SumJob J = p.j[blockIdx.y];
  const int bin = blockIdx.x * 256 + threadIdx.x;
  if (bin >= J.nbins) return;
  int s = 0;
  for (int b = 0; b < J.nblocks; ++b) s += J.H[(size_t)b * J.nbins + bin];
  J.tot[bin] = s;
}

// ---------------- exclusive scan (one 512-thread block per relation, n<=16384) -------
struct ScanRel { const int* tot; int* rowstart; int n; };
struct ScanParams { ScanRel r[NREL]; };

__global__ __launch_bounds__(512) void k_scan(ScanParams p) {
  ScanRel R = p.r[blockIdx.x];
  const int t = threadIdx.x;
  const int lane = t & 63, wv = t >> 6;
  const int base = t * 32;
  int v[32];
  int s = 0;
#pragma unroll
  for (int i = 0; i < 32; ++i) {
    int e = base + i;
    int x = (e < R.n) ? R.tot[e] : 0;
    v[i] = s; s += x;
  }
  int inc = s;
#pragma unroll
  for (int off = 1; off < 64; off <<= 1) {
    int u = __shfl_up(inc, off);
    if (lane >= off) inc += u;
  }
  __shared__ int wsum[8];
  if (lane == 63) wsum[wv] = inc;
  __syncthreads();
  int carry = 0, total = 0;
#pragma unroll
  for (int w = 0; w < 8; ++w) {
    int x = wsum[w];
    if (w < wv) carry += x;
    total += x;
  }
  const int tb = carry + (inc - s);
#pragma unroll
  for (int i = 0; i < 32; ++i) {
    int e = base + i;
    if (e < R.n) R.rowstart[e] = tb + v[i];
  }
  if (t == 0) R.rowstart[R.n] = total;
}

// ---------------- per-bin exclusive prefix over chunk-blocks (in place, u16) ---------
struct BasesJob { unsigned short* H; int nbins; int nblocks; };
struct BasesParams { BasesJob j[NREL]; };

__global__ __launch_bounds__(256) void k_bases(BasesParams p) {
  BasesJob J = p.j[blockIdx.y];
  const int bin = blockIdx.x * 256 + threadIdx.x;
  if (bin >= J.nbins) return;
  int run = 0;
  for (int b = 0; b < J.nblocks; ++b) {
    const size_t o = (size_t)b * J.nbins + bin;
    const int c = J.H[o];
    J.H[o] = (unsigned short)run;
    run += c;
  }
}

// ---------------- place edges via LDS cursors (no global atomics, u16 csr) -----------
struct PlaceJob { const int* src; const int* dst; const unsigned short* Hpre; const int* rowstart;
                  unsigned short* csr; int n_edges; int nbins; };
struct PlaceParams { PlaceJob j[NREL]; };

__global__ __launch_bounds__(1024) void k_place(PlaceParams p) {
  PlaceJob J = p.j[blockIdx.y];
  const int e0 = blockIdx.x * CCHUNK;
  if (e0 >= J.n_edges) return;
  __shared__ int lb[MAXBINS];
  const int t = threadIdx.x;
  const unsigned short* Hrow = J.Hpre + (size_t)blockIdx.x * J.nbins;
  for (int d = t; d < J.nbins; d += 1024) lb[d] = J.rowstart[d] + (int)Hrow[d];
  __syncthreads();
  const int eend = (e0 + CCHUNK < J.n_edges) ? e0 + CCHUNK : J.n_edges;
  for (int e = e0 + t; e < eend; e += 1024) {
    const int d = J.dst[e];
    const int pos = atomicAdd(&lb[d], 1);
    J.csr[pos] = (unsigned short)J.src[e];
  }
}

// ---------------- W -> W^T bf16 ----------------
struct WtParams { const float* W[NREL]; unsigned short* WT[NREL]; };

__global__ __launch_bounds__(256) void k_wt(WtParams p) {
  const int r = blockIdx.y;
  const int g = blockIdx.x * 256 + threadIdx.x;  // 0..16383
  const int k = g >> 5;
  const int n0 = (g & 31) * 4;
  const float4 w = *(const float4*)(p.W[r] + (size_t)k * OUT_F + n0);
  unsigned short* WT = p.WT[r];
  WT[(size_t)(n0 + 0) * IN_F + k] = f2bf(w.x);
  WT[(size_t)(n0 + 1) * IN_F + k] = f2bf(w.y);
  WT[(size_t)(n0 + 2) * IN_F + k] = f2bf(w.z);
  WT[(size_t)(n0 + 3) * IN_F + k] = f2bf(w.w);
}

// ---------------- y_r = (hb @ W_r) * deg_out^-1/2 — m97-style gload_lds MFMA ---------
// BK=64 (128B rows, 8 x 16B slots), both-sides XOR swizzle slot^=(row&7):
// linear LDS dest (gload_lds requirement) + inverse-swizzled global source + swizzled
// ds_read => ds_read_b128 at 2 lanes/bank (free).
struct GemmRel { const unsigned short* hb; const unsigned short* WT; unsigned short* y;
                 const int* deg_out; int n_src; };
struct GemmParams { GemmRel r[NREL]; };

#define GEMM_JOBS 723

__global__ __launch_bounds__(256) void k_gemm(GemmParams p) {
  // bijective XCD swizzle: orig -> jobid (m204)
  const int orig = blockIdx.x;
  const int xcd = orig & 7;
  const int i8 = orig >> 3;
  const int q = GEMM_JOBS / 8, rm = GEMM_JOBS % 8;   // 90, 3
  const int g = (xcd < rm ? xcd * (q + 1) : rm * (q + 1) + (xcd - rm) * q) + i8;
  // decode jobid -> (rel, rowtile); same-tile jobs adjacent for L2 A-reuse
  static const int dr[4] = {0, 2, 4, 6};
  static const int pr[3] = {1, 3, 8};
  static const int xr[2] = {5, 9};
  int rel, tile;
  if (g < 252)      { rel = dr[g & 3]; tile = g >> 2; }
  else if (g < 627) { int u = g - 252; rel = pr[u % 3]; tile = u / 3; }
  else if (g < 691) { int u = g - 627; rel = xr[u & 1]; tile = u >> 1; }
  else              { rel = 7; tile = g - 691; }

  const GemmRel R = p.r[rel];
  const int m0 = tile * 128;

  __shared__ unsigned short As[128 * 64];   // [row][64 shorts], slots XOR-swizzled
  __shared__ unsigned short Bs[128 * 64];

  const int t = threadIdx.x;
  const int lane = t & 63, wid = t >> 6;
  const int wm = (wid >> 1) * 64, wn = (wid & 1) * 64;
  const int l16 = lane & 15;
  const int fcol = lane >> 4;         // 0..3 (16B group within 32-elem K window)
  const int srow8 = lane >> 3;        // staging: row within 8-row group
  const int slot  = lane & 7;         // staging: 16B slot
  const int scol  = (slot ^ srow8) * 8;  // inverse-swizzled source element offset

  // per-lane global bases for the 4 staging instructions (A clamped on tail tile)
  const unsigned short* ga[4];
  const unsigned short* gb[4];
#pragma unroll
  for (int i = 0; i < 4; ++i) {
    const int lrow = wid * 32 + i * 8 + srow8;   // 0..127
    int grow = m0 + lrow;
    if (grow > R.n_src - 1) grow = R.n_src - 1;  // clamp: finite garbage, rows not stored
    ga[i] = R.hb + (size_t)grow * IN_F + scol;
    gb[i] = R.WT + (size_t)lrow * IN_F + scol;
  }

  f32x4 acc[4][4];
#pragma unroll
  for (int i = 0; i < 4; ++i)
#pragma unroll
    for (int j = 0; j < 4; ++j) acc[i][j] = (f32x4){0.f, 0.f, 0.f, 0.f};

#pragma unroll 1
  for (int s = 0; s < 8; ++s) {
    const int k0 = s * 64;
#pragma unroll
    for (int i = 0; i < 4; ++i) {
      gl_lds16(ga[i] + k0, &As[(wid * 32 + i * 8) * 64]);
      gl_lds16(gb[i] + k0, &Bs[(wid * 32 + i * 8) * 64]);
    }
    __syncthreads();   // drains vmcnt(0): staged tile visible
#pragma unroll
    for (int kk = 0; kk < 2; ++kk) {
      const int csl = ((kk * 4 + fcol) ^ (l16 & 7)) * 8;  // swizzled slot (row&7 == l16&7)
      short8 af[4], bf[4];
#pragma unroll
      for (int f = 0; f < 4; ++f) {
        af[f] = *(const short8*)&As[(wm + f * 16 + l16) * 64 + csl];
        bf[f] = *(const short8*)&Bs[(wn + f * 16 + l16) * 64 + csl];
      }
#pragma unroll
      for (int i = 0; i < 4; ++i)
#pragma unroll
        for (int j = 0; j < 4; ++j)
          acc[i][j] = __builtin_amdgcn_mfma_f32_16x16x32_bf16(af[i], bf[j], acc[i][j], 0, 0, 0);
    }
    __syncthreads();   // fragment reads done before next stage overwrites
  }

  const int r4 = (lane >> 4) * 4;  // C/D: col=lane&15, row=(lane>>4)*4+q
#pragma unroll
  for (int i = 0; i < 4; ++i) {
#pragma unroll
    for (int qq = 0; qq < 4; ++qq) {
      const int row = m0 + wm + i * 16 + r4 + qq;
      if (row < R.n_src) {
        const int d = R.deg_out[row];
        const float sc = rsqrtf((float)(d > 1 ? d : 1));
#pragma unroll
        for (int j = 0; j < 4; ++j) {
          const int col = wn + j * 16 + l16;
          R.y[(size_t)row * OUT_F + col] = f2bf(acc[i][j][qq] * sc);
        }
      }
    }
  }
}

// ---------------- gather-aggregate + bias + relu (one wave per node, 16 lanes/row) ---
struct AggRel { const int* rowstart; const unsigned short* csr; const unsigned short* y; const float* b; };
struct AggType { AggRel r[4]; int n_rels; int n_nodes; float* out; };
struct AggParams { AggType t[4]; };

__global__ __launch_bounds__(256) void k_aggregate(AggParams p) {
  const AggType& T = p.t[blockIdx.y];
  const int node = blockIdx.x * 4 + (threadIdx.x >> 6);
  if (node >= T.n_nodes) return;
  const int lane = threadIdx.x & 63;
  const int quarter = lane >> 4;        // 0..3: interleaved edge streams
  const int c8 = (lane & 15) * 8;       // 8 columns per lane
  float ac[8] = {0,0,0,0,0,0,0,0};
  float bs[8] = {0,0,0,0,0,0,0,0};
#pragma unroll
  for (int rr = 0; rr < 4; ++rr) {
    if (rr < T.n_rels) {
      const AggRel R = T.r[rr];
      const int lo = R.rowstart[node];
      const int hi = R.rowstart[node + 1];
      float rx[8] = {0,0,0,0,0,0,0,0};
      int k = lo + quarter;
      for (; k + 12 < hi; k += 16) {   // 16 edges in flight per wave
        const int s0 = R.csr[k];
        const int s1 = R.csr[k + 4];
        const int s2 = R.csr[k + 8];
        const int s3 = R.csr[k + 12];
        const uint4 u0 = *(const uint4*)(R.y + (size_t)s0 * OUT_F + c8);
        const uint4 u1 = *(const uint4*)(R.y + (size_t)s1 * OUT_F + c8);
        const uint4 u2 = *(const uint4*)(R.y + (size_t)s2 * OUT_F + c8);
        const uint4 u3 = *(const uint4*)(R.y + (size_t)s3 * OUT_F + c8);
        add8(rx, u0); add8(rx, u1); add8(rx, u2); add8(rx, u3);
      }
      for (; k < hi; k += 4) {
        const int s0 = R.csr[k];
        const uint4 u0 = *(const uint4*)(R.y + (size_t)s0 * OUT_F + c8);
        add8(rx, u0);
      }
      const int deg = hi - lo;
      const float sc = rsqrtf((float)(deg > 1 ? deg : 1));
#pragma unroll
      for (int i = 0; i < 8; ++i) ac[i] = fmaf(rx[i], sc, ac[i]);
      const float4 b0 = *(const float4*)(R.b + c8);
      const float4 b1 = *(const float4*)(R.b + c8 + 4);
      bs[0] += b0.x; bs[1] += b0.y; bs[2] += b0.z; bs[3] += b0.w;
      bs[4] += b1.x; bs[5] += b1.y; bs[6] += b1.z; bs[7] += b1.w;
    }
  }
#pragma unroll
  for (int i = 0; i < 8; ++i) {
    ac[i] += __shfl_xor(ac[i], 16);
    ac[i] += __shfl_xor(ac[i], 32);
    ac[i] += bs[i];
    ac[i] = ac[i] > 0.f ? ac[i] : 0.f;
  }
  if (quarter == 0) {
    float* dst = T.out + (size_t)node * OUT_F + c8;
    float4 o0 = {ac[0], ac[1], ac[2], ac[3]};
    float4 o1 = {ac[4], ac[5], ac[6], ac[7]};
    *(float4*)dst = o0;
    *(float4*)(dst + 4) = o1;
  }
}

// ---------------- host ----------------
extern "C" void kernel_launch(void* const* d_in, const int* in_sizes, int n_in,
                              void* d_out, int out_size, void* d_ws, size_t ws_size,
                              hipStream_t stream) {
  const float* h[4];
  for (int i = 0; i < 4; ++i) h[i] = (const float*)d_in[i];
  const float* W[NREL]; const float* b[NREL];
  const int* src[NREL]; const int* dst[NREL];
  for (int r = 0; r < NREL; ++r) {
    W[r]   = (const float*)d_in[4 + 2 * r];
    b[r]   = (const float*)d_in[5 + 2 * r];
    src[r] = (const int*)d_in[24 + 2 * r];
    dst[r] = (const int*)d_in[25 + 2 * r];
  }
  float* out = (float*)d_out;

  int nblk[NREL];
  for (int r = 0; r < NREL; ++r) nblk[r] = (kNEdges[r] + CCHUNK - 1) / CCHUNK;

  char* ws = (char*)d_ws;
  size_t off = 0;
  auto alloc = [&](size_t bytes) -> char* {
    char* p = ws + off;
    off = (off + bytes + 255) & ~(size_t)255;
    return p;
  };
  int* degO[NREL];
  { char* base = alloc((size_t)92000 * 4); size_t o = 0;
    for (int r = 0; r < NREL; ++r) { degO[r] = (int*)(base + o); o += (size_t)kNSrc[r] * 4; } }
  int* totI[NREL];
  { char* base = alloc((size_t)92000 * 4); size_t o = 0;
    for (int r = 0; r < NREL; ++r) { totI[r] = (int*)(base + o); o += (size_t)kNDst[r] * 4; } }
  int* rowst[NREL];
  { char* base = alloc((size_t)(92000 + NREL) * 4); size_t o = 0;
    for (int r = 0; r < NREL; ++r) { rowst[r] = (int*)(base + o); o += (size_t)(kNDst[r] + 1) * 4; } }
  unsigned short* csr[NREL];
  { char* base = alloc((size_t)2500000 * 2); size_t o = 0;
    for (int r = 0; r < NREL; ++r) { csr[r] = (unsigned short*)(base + o); o += (size_t)kNEdges[r] * 2; } }
  unsigned short* Hsrc[NREL]; unsigned short* Hdst[NREL];
  { size_t tot = 0;
    for (int r = 0; r < NREL; ++r) tot += (size_t)nblk[r] * (kNSrc[r] + kNDst[r]);
    char* base = alloc(tot * 2); size_t o = 0;
    for (int r = 0; r < NREL; ++r) { Hsrc[r] = (unsigned short*)(base + o); o += (size_t)nblk[r] * kNSrc[r] * 2; }
    for (int r = 0; r < NREL; ++r) { Hdst[r] = (unsigned short*)(base + o); o += (size_t)nblk[r] * kNDst[r] * 2; } }
  unsigned short* y[NREL];
  { char* base = alloc((size_t)92000 * OUT_F * 2); size_t o = 0;
    for (int r = 0; r < NREL; ++r) { y[r] = (unsigned short*)(base + o); o += (size_t)kNSrc[r] * OUT_F * 2; } }
  unsigned short* WT[NREL];
  { char* base = alloc((size_t)NREL * IN_F * OUT_F * 2); size_t o = 0;
    for (int r = 0; r < NREL; ++r) { WT[r] = (unsigned short*)(base + o); o += (size_t)IN_F * OUT_F * 2; } }
  unsigned short* hb = (unsigned short*)alloc((size_t)32000 * IN_F * 2);  // bf16 h, all types

  // h -> bf16
  CvtParams cvp;
  for (int ty = 0; ty < 4; ++ty) {
    cvp.src[ty] = h[ty];
    cvp.dst[ty] = hb + kHbOff[ty];
    cvp.n8[ty] = kNNodes[ty] * IN_F / 8;
  }
  k_cvt<<<dim3((16000 * IN_F / 8 + 255) / 256, 4), 256, 0, stream>>>(cvp);

  WtParams wp;
  for (int r = 0; r < NREL; ++r) { wp.W[r] = W[r]; wp.WT[r] = WT[r]; }
  k_wt<<<dim3(64, NREL), 256, 0, stream>>>(wp);

  int maxblk = 0;
  for (int r = 0; r < NREL; ++r) if (nblk[r] > maxblk) maxblk = nblk[r];

  CountParams cp;
  for (int r = 0; r < NREL; ++r) {
    cp.j[r]        = CountJob{src[r], Hsrc[r], kNEdges[r], kNSrc[r]};
    cp.j[NREL + r] = CountJob{dst[r], Hdst[r], kNEdges[r], kNDst[r]};
  }
  k_count<<<dim3(maxblk, 2 * NREL), 1024, 0, stream>>>(cp);

  SumParams sp2;
  for (int r = 0; r < NREL; ++r) {
    sp2.j[r]        = SumJob{Hsrc[r], degO[r], kNSrc[r], nblk[r]};
    sp2.j[NREL + r] = SumJob{Hdst[r], totI[r], kNDst[r], nblk[r]};
  }
  k_sum<<<dim3((16000 + 255) / 256, 2 * NREL), 256, 0, stream>>>(sp2);

  ScanParams sp;
  for (int r = 0; r < NREL; ++r) sp.r[r] = ScanRel{totI[r], rowst[r], kNDst[r]};
  k_scan<<<NREL, 512, 0, stream>>>(sp);

  BasesParams bp;
  for (int r = 0; r < NREL; ++r) bp.j[r] = BasesJob{Hdst[r], kNDst[r], nblk[r]};
  k_bases<<<dim3((16000 + 255) / 256, NREL), 256, 0, stream>>>(bp);

  PlaceParams pp;
  for (int r = 0; r < NREL; ++r)
    pp.j[r] = PlaceJob{src[r], dst[r], Hdst[r], rowst[r], csr[r], kNEdges[r], kNDst[r]};
  k_place<<<dim3(maxblk, NREL), 1024, 0, stream>>>(pp);

  GemmParams gp;
  for (int r = 0; r < NREL; ++r)
    gp.r[r] = GemmRel{hb + kHbOff[kRelSrcType[r]], WT[r], y[r], degO[r], kNSrc[r]};
  k_gemm<<<GEMM_JOBS, 256, 0, stream>>>(gp);

  AggParams ap;
  for (int ti = 0; ti < 4; ++ti) {
    AggType& T = ap.t[ti];
    T.n_nodes = kNNodes[ti];
    T.n_rels = kNDstRels[ti];
    T.out = out + kOutOff[ti];
    for (int j = 0; j < 4; ++j) {
      int r = kDstRels[ti][j];
      if (r < 0) r = kDstRels[ti][0];
      T.r[j] = AggRel{rowst[r], csr[r], y[r], b[r]};
    }
  }
  k_aggregate<<<dim3((16000 + 3) / 4, 4), 256, 0, stream>>>(ap);
}

// Round 9
// 196.226 us; speedup vs baseline: 1.1870x; 1.0159x over previous
//
#include <hip/hip_runtime.h>
#include <cstddef>
#include <cstdint>

#define IN_F 512
#define OUT_F 128
#define NREL 10
#define MAXBINS 16000
#define CCHUNK 32768

typedef __attribute__((ext_vector_type(8))) short short8;
typedef __attribute__((ext_vector_type(4))) float f32x4;
typedef __bf16 bf16x2 __attribute__((ext_vector_type(2)));
typedef float f32x2 __attribute__((ext_vector_type(2)));

static const int kNSrc[NREL]   = {8000,16000,8000,16000,8000,4000,8000,4000,16000,4000};
static const int kNDst[NREL]   = {8000,16000,16000,8000,4000,8000,4000,8000,4000,16000};
static const int kNEdges[NREL] = {200000,800000,400000,400000,100000,100000,100000,100000,150000,150000};
static const int kRelSrcType[NREL] = {0,1,0,1,0,2,0,3,1,2};
static const int kNNodes[4] = {8000,16000,4000,4000};
static const size_t kOutOff[4] = {0, 8000ull*OUT_F, 24000ull*OUT_F, 28000ull*OUT_F};
static const size_t kHbOff[4] = {0, 8000ull*IN_F, 24000ull*IN_F, 28000ull*IN_F};
static const int kDstRels[4][4] = {{0,3,5,7},{1,2,9,-1},{4,8,-1,-1},{6,-1,-1,-1}};
static const int kNDstRels[4] = {4,3,2,1};

__device__ __forceinline__ unsigned short f2bf(float f) {
  union { float f; unsigned u; } v; v.f = f;
  unsigned r = v.u + 0x7fffu + ((v.u >> 16) & 1u);
  return (unsigned short)(r >> 16);
}
// packed bf16-pair -> f32-pair accumulate (lowers to cvt_pk/pk_add where available)
__device__ __forceinline__ void acc8(f32x2* a, uint4 u) {
  union { unsigned v; bf16x2 h; } c0, c1, c2, c3;
  c0.v = u.x; c1.v = u.y; c2.v = u.z; c3.v = u.w;
  a[0] += __builtin_convertvector(c0.h, f32x2);
  a[1] += __builtin_convertvector(c1.h, f32x2);
  a[2] += __builtin_convertvector(c2.h, f32x2);
  a[3] += __builtin_convertvector(c3.h, f32x2);
}
// async global->LDS, 16B/lane; LDS dest = uniform base + lane*16 (m97 pattern)
__device__ __forceinline__ void gl_lds16(const unsigned short* g, unsigned short* l) {
  __builtin_amdgcn_global_load_lds(
      (const __attribute__((address_space(1))) unsigned int*)(g),
      (__attribute__((address_space(3))) unsigned int*)(l), 16, 0, 0);
}

// ---------------- fused prep: count jobs (y 0..19) + h->bf16 cvt (20..23) + W^T (24..33)
struct CountJob { const int* idx; unsigned short* H; int n_edges; int nbins; };
struct PrepParams {
  CountJob cj[2 * NREL];
  const float* csrc[4]; unsigned short* cdst[4]; int cn8[4];
  const float* W[NREL]; unsigned short* WT[NREL];
};

__global__ __launch_bounds__(1024) void k_prep(PrepParams p) {
  const int job = blockIdx.y;
  const int t = threadIdx.x;
  if (job < 2 * NREL) {
    // per-chunk LDS histogram -> coalesced u16 H row (no global atomics)
    CountJob J = p.cj[job];
    const int e0 = blockIdx.x * CCHUNK;
    if (e0 >= J.n_edges) return;
    __shared__ int lb[MAXBINS];
    for (int d = t; d < J.nbins; d += 1024) lb[d] = 0;
    __syncthreads();
    const int eend = (e0 + CCHUNK < J.n_edges) ? e0 + CCHUNK : J.n_edges;
    for (int e = e0 + t; e < eend; e += 1024) atomicAdd(&lb[J.idx[e]], 1);
    __syncthreads();
    unsigned short* Hrow = J.H + (size_t)blockIdx.x * J.nbins;
    for (int d = t; d < J.nbins; d += 1024) Hrow[d] = (unsigned short)lb[d];
  } else if (job < 2 * NREL + 4) {
    // h (f32) -> hb (bf16), grid-stride over vec8
    const int ty = job - 2 * NREL;
    const int stride = gridDim.x * 1024;
    const int n8 = p.cn8[ty];
    const float* src = p.csrc[ty];
    unsigned short* dst = p.cdst[ty];
    for (int i = blockIdx.x * 1024 + t; i < n8; i += stride) {
      const float4 v0 = *(const float4*)(src + (size_t)i * 8);
      const float4 v1 = *(const float4*)(src + (size_t)i * 8 + 4);
      uint4 o;
      o.x = (unsigned)f2bf(v0.x) | ((unsigned)f2bf(v0.y) << 16);
      o.y = (unsigned)f2bf(v0.z) | ((unsigned)f2bf(v0.w) << 16);
      o.z = (unsigned)f2bf(v1.x) | ((unsigned)f2bf(v1.y) << 16);
      o.w = (unsigned)f2bf(v1.z) | ((unsigned)f2bf(v1.w) << 16);
      *(uint4*)(dst + (size_t)i * 8) = o;
    }
  } else {
    // W -> W^T bf16, grid-stride
    const int r = job - 2 * NREL - 4;
    const int stride = gridDim.x * 1024;
    const float* W = p.W[r];
    unsigned short* WT = p.WT[r];
    for (int g = blockIdx.x * 1024 + t; g < IN_F * OUT_F / 4; g += stride) {
      const int k = g >> 5;
      const int n0 = (g & 31) * 4;
      const float4 w = *(const float4*)(W + (size_t)k * OUT_F + n0);
      WT[(size_t)(n0 + 0) * IN_F + k] = f2bf(w.x);
      WT[(size_t)(n0 + 1) * IN_F + k] = f2bf(w.y);
      WT[(size_t)(n0 + 2) * IN_F + k] = f2bf(w.z);
      WT[(size_t)(n0 + 3) * IN_F + k] = f2bf(w.w);
    }
  }
}

// ---------------- column-sum of H -> totals, coalesced --------------------------------
struct SumJob { const unsigned short* H; int* tot; int nbins; int nblocks; };
struct SumParams { SumJob j[2 * NREL]; };

__global__ __launch_bounds__(256) void k_sum(SumParams p) {
  SumJob J = p.j[blockIdx.y];
  const int bin = blockIdx.x * 256 + threadIdx.x;
  if (bin >= J.nbins) return;
  int s = 0;
  for (int b = 0; b < J.nblocks; ++b) s += J.H[(size_t)b * J.nbins + bin];
  J.tot[bin] = s;
}

// ---------------- exclusive scan (one 512-thread block per relation, n<=16384) -------
struct ScanRel { const int* tot; int* rowstart; int n; };
struct ScanParams { ScanRel r[NREL]; };

__global__ __launch_bounds__(512) void k_scan(ScanParams p) {
  ScanRel R = p.r[blockIdx.x];
  const int t = threadIdx.x;
  const int lane = t & 63, wv = t >> 6;
  const int base = t * 32;
  int v[32];
  int s = 0;
#pragma unroll
  for (int i = 0; i < 32; ++i) {
    int e = base + i;
    int x = (e < R.n) ? R.tot[e] : 0;
    v[i] = s; s += x;
  }
  int inc = s;
#pragma unroll
  for (int off = 1; off < 64; off <<= 1) {
    int u = __shfl_up(inc, off);
    if (lane >= off) inc += u;
  }
  __shared__ int wsum[8];
  if (lane == 63) wsum[wv] = inc;
  __syncthreads();
  int carry = 0, total = 0;
#pragma unroll
  for (int w = 0; w < 8; ++w) {
    int x = wsum[w];
    if (w < wv) carry += x;
    total += x;
  }
  const int tb = carry + (inc - s);
#pragma unroll
  for (int i = 0; i < 32; ++i) {
    int e = base + i;
    if (e < R.n) R.rowstart[e] = tb + v[i];
  }
  if (t == 0) R.rowstart[R.n] = total;
}

// ---------------- per-bin exclusive prefix over chunk-blocks (in place, u16) ---------
struct BasesJob { unsigned short* H; int nbins; int nblocks; };
struct BasesParams { BasesJob j[NREL]; };

__global__ __launch_bounds__(256) void k_bases(BasesParams p) {
  BasesJob J = p.j[blockIdx.y];
  const int bin = blockIdx.x * 256 + threadIdx.x;
  if (bin >= J.nbins) return;
  int run = 0;
  for (int b = 0; b < J.nblocks; ++b) {
    const size_t o = (size_t)b * J.nbins + bin;
    const int c = J.H[o];
    J.H[o] = (unsigned short)run;
    run += c;
  }
}

// ---------------- place edges via LDS cursors (no global atomics, u16 csr) -----------
struct PlaceJob { const int* src; const int* dst; const unsigned short* Hpre; const int* rowstart;
                  unsigned short* csr; int n_edges; int nbins; };
struct PlaceParams { PlaceJob j[NREL]; };

__global__ __launch_bounds__(1024) void k_place(PlaceParams p) {
  PlaceJob J = p.j[blockIdx.y];
  const int e0 = blockIdx.x * CCHUNK;
  if (e0 >= J.n_edges) return;
  __shared__ int lb[MAXBINS];
  const int t = threadIdx.x;
  const unsigned short* Hrow = J.Hpre + (size_t)blockIdx.x * J.nbins;
  for (int d = t; d < J.nbins; d += 1024) lb[d] = J.rowstart[d] + (int)Hrow[d];
  __syncthreads();
  const int eend = (e0 + CCHUNK < J.n_edges) ? e0 + CCHUNK : J.n_edges;
  for (int e = e0 + t; e < eend; e += 1024) {
    const int d = J.dst[e];
    const int pos = atomicAdd(&lb[d], 1);
    J.csr[pos] = (unsigned short)J.src[e];
  }
}

// ---------------- y_r = (hb @ W_r) * deg_out^-1/2 — m97-style gload_lds MFMA ---------
struct GemmRel { const unsigned short* hb; const unsigned short* WT; unsigned short* y;
                 const int* deg_out; int n_src; };
struct GemmParams { GemmRel r[NREL]; };

#define GEMM_JOBS 723

__global__ __launch_bounds__(256) void k_gemm(GemmParams p) {
  // bijective XCD swizzle: orig -> jobid (m204)
  const int orig = blockIdx.x;
  const int xcd = orig & 7;
  const int i8 = orig >> 3;
  const int q = GEMM_JOBS / 8, rm = GEMM_JOBS % 8;   // 90, 3
  const int g = (xcd < rm ? xcd * (q + 1) : rm * (q + 1) + (xcd - rm) * q) + i8;
  // decode jobid -> (rel, rowtile); same-tile jobs adjacent for L2 A-reuse
  static const int dr[4] = {0, 2, 4, 6};
  static const int pr[3] = {1, 3, 8};
  static const int xr[2] = {5, 9};
  int rel, tile;
  if (g < 252)      { rel = dr[g & 3]; tile = g >> 2; }
  else if (g < 627) { int u = g - 252; rel = pr[u % 3]; tile = u / 3; }
  else if (g < 691) { int u = g - 627; rel = xr[u & 1]; tile = u >> 1; }
  else              { rel = 7; tile = g - 691; }

  const GemmRel R = p.r[rel];
  const int m0 = tile * 128;

  __shared__ unsigned short As[128 * 64];   // [row][64 shorts], slots XOR-swizzled
  __shared__ unsigned short Bs[128 * 64];

  const int t = threadIdx.x;
  const int lane = t & 63, wid = t >> 6;
  const int wm = (wid >> 1) * 64, wn = (wid & 1) * 64;
  const int l16 = lane & 15;
  const int fcol = lane >> 4;         // 0..3 (16B group within 32-elem K window)
  const int srow8 = lane >> 3;        // staging: row within 8-row group
  const int slot  = lane & 7;         // staging: 16B slot
  const int scol  = (slot ^ srow8) * 8;  // inverse-swizzled source element offset

  const unsigned short* ga[4];
  const unsigned short* gb[4];
#pragma unroll
  for (int i = 0; i < 4; ++i) {
    const int lrow = wid * 32 + i * 8 + srow8;   // 0..127
    int grow = m0 + lrow;
    if (grow > R.n_src - 1) grow = R.n_src - 1;  // clamp: finite garbage, rows not stored
    ga[i] = R.hb + (size_t)grow * IN_F + scol;
    gb[i] = R.WT + (size_t)lrow * IN_F + scol;
  }

  f32x4 acc[4][4];
#pragma unroll
  for (int i = 0; i < 4; ++i)
#pragma unroll
    for (int j = 0; j < 4; ++j) acc[i][j] = (f32x4){0.f, 0.f, 0.f, 0.f};

#pragma unroll 1
  for (int s = 0; s < 8; ++s) {
    const int k0 = s * 64;
#pragma unroll
    for (int i = 0; i < 4; ++i) {
      gl_lds16(ga[i] + k0, &As[(wid * 32 + i * 8) * 64]);
      gl_lds16(gb[i] + k0, &Bs[(wid * 32 + i * 8) * 64]);
    }
    __syncthreads();   // drains vmcnt(0): staged tile visible
#pragma unroll
    for (int kk = 0; kk < 2; ++kk) {
      const int csl = ((kk * 4 + fcol) ^ (l16 & 7)) * 8;  // swizzled slot
      short8 af[4], bf[4];
#pragma unroll
      for (int f = 0; f < 4; ++f) {
        af[f] = *(const short8*)&As[(wm + f * 16 + l16) * 64 + csl];
        bf[f] = *(const short8*)&Bs[(wn + f * 16 + l16) * 64 + csl];
      }
#pragma unroll
      for (int i = 0; i < 4; ++i)
#pragma unroll
        for (int j = 0; j < 4; ++j)
          acc[i][j] = __builtin_amdgcn_mfma_f32_16x16x32_bf16(af[i], bf[j], acc[i][j], 0, 0, 0);
    }
    __syncthreads();   // fragment reads done before next stage overwrites
  }

  const int r4 = (lane >> 4) * 4;  // C/D: col=lane&15, row=(lane>>4)*4+q
#pragma unroll
  for (int i = 0; i < 4; ++i) {
#pragma unroll
    for (int qq = 0; qq < 4; ++qq) {
      const int row = m0 + wm + i * 16 + r4 + qq;
      if (row < R.n_src) {
        const int d = R.deg_out[row];
        const float sc = rsqrtf((float)(d > 1 ? d : 1));
#pragma unroll
        for (int j = 0; j < 4; ++j) {
          const int col = wn + j * 16 + l16;
          R.y[(size_t)row * OUT_F + col] = f2bf(acc[i][j][qq] * sc);
        }
      }
    }
  }
}

// ---------------- gather-aggregate + bias + relu (one wave per node, 16 lanes/row) ---
struct AggRel { const int* rowstart; const unsigned short* csr; const unsigned short* y; const float* b; };
struct AggType { AggRel r[4]; int n_rels; int n_nodes; float* out; };
struct AggParams { AggType t[4]; };

__global__ __launch_bounds__(256) void k_aggregate(AggParams p) {
  const AggType& T = p.t[blockIdx.y];
  const int node = blockIdx.x * 4 + (threadIdx.x >> 6);
  if (node >= T.n_nodes) return;
  const int lane = threadIdx.x & 63;
  const int quarter = lane >> 4;        // 0..3: interleaved edge streams
  const int c8 = (lane & 15) * 8;       // 8 columns per lane
  f32x2 ac2[4] = {{0.f,0.f},{0.f,0.f},{0.f,0.f},{0.f,0.f}};
  float bs[8] = {0,0,0,0,0,0,0,0};
#pragma unroll
  for (int rr = 0; rr < 4; ++rr) {
    if (rr < T.n_rels) {
      const AggRel R = T.r[rr];
      const int lo = R.rowstart[node];
      const int hi = R.rowstart[node + 1];
      f32x2 rx2[4] = {{0.f,0.f},{0.f,0.f},{0.f,0.f},{0.f,0.f}};
      int k = lo + quarter;
      for (; k + 12 < hi; k += 16) {   // 16 edges in flight per wave
        const int s0 = R.csr[k];
        const int s1 = R.csr[k + 4];
        const int s2 = R.csr[k + 8];
        const int s3 = R.csr[k + 12];
        const uint4 u0 = *(const uint4*)(R.y + (size_t)s0 * OUT_F + c8);
        const uint4 u1 = *(const uint4*)(R.y + (size_t)s1 * OUT_F + c8);
        const uint4 u2 = *(const uint4*)(R.y + (size_t)s2 * OUT_F + c8);
        const uint4 u3 = *(const uint4*)(R.y + (size_t)s3 * OUT_F + c8);
        acc8(rx2, u0); acc8(rx2, u1); acc8(rx2, u2); acc8(rx2, u3);
      }
      for (; k < hi; k += 4) {
        const int s0 = R.csr[k];
        const uint4 u0 = *(const uint4*)(R.y + (size_t)s0 * OUT_F + c8);
        acc8(rx2, u0);
      }
      const int deg = hi - lo;
      const float s = rsqrtf((float)(deg > 1 ? deg : 1));
      const f32x2 sc2 = {s, s};
#pragma unroll
      for (int i = 0; i < 4; ++i) ac2[i] += rx2[i] * sc2;   // v_pk_fma_f32
      const float4 b0 = *(const float4*)(R.b + c8);
      const float4 b1 = *(const float4*)(R.b + c8 + 4);
      bs[0] += b0.x; bs[1] += b0.y; bs[2] += b0.z; bs[3] += b0.w;
      bs[4] += b1.x; bs[5] += b1.y; bs[6] += b1.z; bs[7] += b1.w;
    }
  }
  float ac[8] = {ac2[0].x, ac2[0].y, ac2[1].x, ac2[1].y,
                 ac2[2].x, ac2[2].y, ac2[3].x, ac2[3].y};
#pragma unroll
  for (int i = 0; i < 8; ++i) {
    ac[i] += __shfl_xor(ac[i], 16);
    ac[i] += __shfl_xor(ac[i], 32);
    ac[i] += bs[i];
    ac[i] = ac[i] > 0.f ? ac[i] : 0.f;
  }
  if (quarter == 0) {
    float* dst = T.out + (size_t)node * OUT_F + c8;
    float4 o0 = {ac[0], ac[1], ac[2], ac[3]};
    float4 o1 = {ac[4], ac[5], ac[6], ac[7]};
    *(float4*)dst = o0;
    *(float4*)(dst + 4) = o1;
  }
}

// ---------------- host ----------------
extern "C" void kernel_launch(void* const* d_in, const int* in_sizes, int n_in,
                              void* d_out, int out_size, void* d_ws, size_t ws_size,
                              hipStream_t stream) {
  const float* h[4];
  for (int i = 0; i < 4; ++i) h[i] = (const float*)d_in[i];
  const float* W[NREL]; const float* b[NREL];
  const int* src[NREL]; const int* dst[NREL];
  for (int r = 0; r < NREL; ++r) {
    W[r]   = (const float*)d_in[4 + 2 * r];
    b[r]   = (const float*)d_in[5 + 2 * r];
    src[r] = (const int*)d_in[24 + 2 * r];
    dst[r] = (const int*)d_in[25 + 2 * r];
  }
  float* out = (float*)d_out;

  int nblk[NREL];
  for (int r = 0; r < NREL; ++r) nblk[r] = (kNEdges[r] + CCHUNK - 1) / CCHUNK;

  char* ws = (char*)d_ws;
  size_t off = 0;
  auto alloc = [&](size_t bytes) -> char* {
    char* p = ws + off;
    off = (off + bytes + 255) & ~(size_t)255;
    return p;
  };
  int* degO[NREL];
  { char* base = alloc((size_t)92000 * 4); size_t o = 0;
    for (int r = 0; r < NREL; ++r) { degO[r] = (int*)(base + o); o += (size_t)kNSrc[r] * 4; } }
  int* totI[NREL];
  { char* base = alloc((size_t)92000 * 4); size_t o = 0;
    for (int r = 0; r < NREL; ++r) { totI[r] = (int*)(base + o); o += (size_t)kNDst[r] * 4; } }
  int* rowst[NREL];
  { char* base = alloc((size_t)(92000 + NREL) * 4); size_t o = 0;
    for (int r = 0; r < NREL; ++r) { rowst[r] = (int*)(base + o); o += (size_t)(kNDst[r] + 1) * 4; } }
  unsigned short* csr[NREL];
  { char* base = alloc((size_t)2500000 * 2); size_t o = 0;
    for (int r = 0; r < NREL; ++r) { csr[r] = (unsigned short*)(base + o); o += (size_t)kNEdges[r] * 2; } }
  unsigned short* Hsrc[NREL]; unsigned short* Hdst[NREL];
  { size_t tot = 0;
    for (int r = 0; r < NREL; ++r) tot += (size_t)nblk[r] * (kNSrc[r] + kNDst[r]);
    char* base = alloc(tot * 2); size_t o = 0;
    for (int r = 0; r < NREL; ++r) { Hsrc[r] = (unsigned short*)(base + o); o += (size_t)nblk[r] * kNSrc[r] * 2; }
    for (int r = 0; r < NREL; ++r) { Hdst[r] = (unsigned short*)(base + o); o += (size_t)nblk[r] * kNDst[r] * 2; } }
  unsigned short* y[NREL];
  { char* base = alloc((size_t)92000 * OUT_F * 2); size_t o = 0;
    for (int r = 0; r < NREL; ++r) { y[r] = (unsigned short*)(base + o); o += (size_t)kNSrc[r] * OUT_F * 2; } }
  unsigned short* WT[NREL];
  { char* base = alloc((size_t)NREL * IN_F * OUT_F * 2); size_t o = 0;
    for (int r = 0; r < NREL; ++r) { WT[r] = (unsigned short*)(base + o); o += (size_t)IN_F * OUT_F * 2; } }
  unsigned short* hb = (unsigned short*)alloc((size_t)32000 * IN_F * 2);  // bf16 h, all types

  int maxblk = 0;
  for (int r = 0; r < NREL; ++r) if (nblk[r] > maxblk) maxblk = nblk[r];

  // fused prep: histograms + h->bf16 + W^T
  PrepParams pr;
  for (int r = 0; r < NREL; ++r) {
    pr.cj[r]        = CountJob{src[r], Hsrc[r], kNEdges[r], kNSrc[r]};
    pr.cj[NREL + r] = CountJob{dst[r], Hdst[r], kNEdges[r], kNDst[r]};
  }
  for (int ty = 0; ty < 4; ++ty) {
    pr.csrc[ty] = h[ty];
    pr.cdst[ty] = hb + kHbOff[ty];
    pr.cn8[ty] = kNNodes[ty] * IN_F / 8;
  }
  for (int r = 0; r < NREL; ++r) { pr.W[r] = W[r]; pr.WT[r] = WT[r]; }
  k_prep<<<dim3(maxblk, 2 * NREL + 4 + NREL), 1024, 0, stream>>>(pr);

  SumParams sp2;
  for (int r = 0; r < NREL; ++r) {
    sp2.j[r]        = SumJob{Hsrc[r], degO[r], kNSrc[r], nblk[r]};
    sp2.j[NREL + r] = SumJob{Hdst[r], totI[r], kNDst[r], nblk[r]};
  }
  k_sum<<<dim3((16000 + 255) / 256, 2 * NREL), 256, 0, stream>>>(sp2);

  ScanParams sp;
  for (int r = 0; r < NREL; ++r) sp.r[r] = ScanRel{totI[r], rowst[r], kNDst[r]};
  k_scan<<<NREL, 512, 0, stream>>>(sp);

  BasesParams bp;
  for (int r = 0; r < NREL; ++r) bp.j[r] = BasesJob{Hdst[r], kNDst[r], nblk[r]};
  k_bases<<<dim3((16000 + 255) / 256, NREL), 256, 0, stream>>>(bp);

  PlaceParams pp;
  for (int r = 0; r < NREL; ++r)
    pp.j[r] = PlaceJob{src[r], dst[r], Hdst[r], rowst[r], csr[r], kNEdges[r], kNDst[r]};
  k_place<<<dim3(maxblk, NREL), 1024, 0, stream>>>(pp);

  GemmParams gp;
  for (int r = 0; r < NREL; ++r)
    gp.r[r] = GemmRel{hb + kHbOff[kRelSrcType[r]], WT[r], y[r], degO[r], kNSrc[r]};
  k_gemm<<<GEMM_JOBS, 256, 0, stream>>>(gp);

  AggParams ap;
  for (int ti = 0; ti < 4; ++ti) {
    AggType& T = ap.t[ti];
    T.n_nodes = kNNodes[ti];
    T.n_rels = kNDstRels[ti];
    T.out = out + kOutOff[ti];
    for (int j = 0; j < 4; ++j) {
      int r = kDstRels[ti][j];
      if (r < 0) r = kDstRels[ti][0];
      T.r[j] = AggRel{rowst[r], csr[r], y[r], b[r]};
    }
  }
  k_aggregate<<<dim3((16000 + 3) / 4, 4), 256, 0, stream>>>(ap);
}